// Round 17
// baseline (93.219 us; speedup 1.0000x reference)
//
#include <hip/hip_runtime.h>
#include <hip/hip_bf16.h>

#define NV 100        // n_vars
#define HID 64        // hidden
#define NE 1000       // experts
#define NB 4096       // batch
#define ESPLIT 32     // K-split count
#define BLOBU 3584    // u32/expert: W2 frags only (14336 B)
#define NVP 112       // padded cols in bf16 partials
#define EXPB 14336    // bytes per expert blob

typedef __attribute__((ext_vector_type(8))) short short8;   // MFMA A/B frag
typedef __attribute__((ext_vector_type(8))) unsigned short ushort8;
typedef __attribute__((ext_vector_type(4))) float f32x4;    // MFMA C/D frag
typedef __attribute__((ext_vector_type(2))) float f32x2;    // packed-math pair
typedef __attribute__((ext_vector_type(4))) unsigned u32x4;

__device__ __align__(16) float g_bsum[NV];

__device__ __forceinline__ unsigned short f2bf(float f) {
    return (unsigned short)__builtin_bit_cast(short, (__bf16)f);
}
__device__ __forceinline__ short cvtbf(float f) {
    return __builtin_bit_cast(short, (__bf16)f);
}
__device__ __forceinline__ float bf2f(unsigned short s) {
    union { unsigned u; float f; } v; v.u = ((unsigned)s) << 16;
    return v.f;
}
__device__ __forceinline__ unsigned pkbf(float a, float b) {
    return (unsigned)f2bf(a) | ((unsigned)f2bf(b) << 16);
}

// packed h-pair: {h0,h1} = relu_bf16(cvt_pk(pk_fma(x·w + b)))  [r14-proven]
__device__ __forceinline__ unsigned pk_h(f32x2 xx, f32x2 w, f32x2 b, unsigned zero) {
    f32x2 d;
    asm("v_pk_fma_f32 %0, %1, %2, %3" : "=v"(d) : "v"(xx), "v"(w), "v"(b));
    unsigned u;
    asm("v_cvt_pk_bf16_f32 %0, %1, %2" : "=v"(u) : "v"(d.x), "v"(d.y));
    asm("v_pk_max_i16 %0, %1, %2" : "=v"(u) : "v"(u), "v"(zero));
    return u;
}

// balanced expert split: 26 splits of 32, 6 splits of 28
__device__ __host__ __forceinline__ void esplit_range(int ks, int* pe0, int* pne) {
    int e0 = (ks < 26) ? 32 * ks : 832 + 28 * (ks - 26);
    int ne = (ks < 26) ? 32 : 28;
    *pe0 = e0; *pne = ne;
}

// ---------------- bias: g_bsum[v] = sum_e b2[e*NV + v] ----------------
__global__ void bias_kernel(const float* __restrict__ b2) {
    int v = blockIdx.x;
    float s = 0.f;
    for (int e = threadIdx.x; e < NE; e += 256)
        s += b2[e * NV + v];
    __shared__ float red[4];
    for (int off = 32; off; off >>= 1) s += __shfl_down(s, off, 64);
    if ((threadIdx.x & 63) == 0) red[threadIdx.x >> 6] = s;
    __syncthreads();
    if (threadIdx.x == 0) g_bsum[v] = red[0] + red[1] + red[2] + red[3];
}

// ---------------- init (fallback path only) ----------------
__global__ void init_kernel(float* __restrict__ out) {
    int idx = blockIdx.x * 256 + threadIdx.x;
    if (idx < NB * NV) out[idx] = g_bsum[idx % NV];
}

// ---------------- prepass: W2 -> frag-contiguous bf16, 14336 B/expert ----------------
__global__ void prepass7(const float* __restrict__ W2, unsigned* __restrict__ blob) {
    __shared__ float t[HID][NV + 1];
    int e = blockIdx.x;
    const float* src = W2 + (size_t)e * (HID * NV);
    for (int i = threadIdx.x; i < HID * NV; i += 256) {
        int hh = i / NV;
        int v = i - hh * NV;
        t[hh][v] = src[i];
    }
    __syncthreads();
    unsigned* dst = blob + (size_t)e * BLOBU;
    for (int o = threadIdx.x; o < BLOBU; o += 256) {
        int f = o >> 8;
        int r = o & 255;
        int l = r >> 2;
        int q = r & 3;
        int ksh = f / 7, tt = f - 7 * ksh;
        int kg = l >> 4, lrow = l & 15;
        int h0 = ksh * 32 + kg * 8 + 2 * q;
        int v = tt * 16 + lrow;
        unsigned val = 0;
        if (v < NV) val = pkbf(t[h0][v], t[h0 + 1][v]);
        dst[o] = val;
    }
}

// ---------------- main: BM=128, 4 waves x 32 rows, LDS-B dbuf, 3 blocks/CU ----------------
// LDS: [0,14336) buf0 | [14336,28672) buf1 | [28672,36864) xts | [36864,45056) w1l | [45056,53248) b1l
__global__ __launch_bounds__(256, 3) void moe17(
    const float* __restrict__ x, const float* __restrict__ W1,
    const float* __restrict__ b1, const unsigned* __restrict__ blob,
    unsigned short* __restrict__ part)
{
    __shared__ __align__(16) unsigned char smem[53248];
    unsigned short* xts = (unsigned short*)(smem + 28672);   // [32][128] permuted bf16 x^T
    float* w1l = (float*)(smem + 36864);                     // [32][64] f32
    float* b1l = (float*)(smem + 45056);                     // [32][64] f32

    const int bid = blockIdx.x;
    const int xcd = bid & 7;
    const int jj  = bid >> 3;              // 0..127
    const int ks  = xcd * 4 + (jj & 3);    // 4 consecutive ksplits per XCD (L2 locality)
    const int mb  = jj >> 2;               // 0..31

    const int tid  = threadIdx.x;
    const int lane = tid & 63;
    const int wave = tid >> 6;             // 0..3, rows wave*32 .. +31
    const int lrow = lane & 15;
    const int kg   = lane >> 4;

    const int row0 = mb * 128;
    int e0, ne; esplit_range(ks, &e0, &ne);

    // ---- stage x permuted: row r -> slot (r>>5)*32 + (r&15)*2 + ((r>>4)&1) ----
    // hot read: one u32 at [e*128 + wave*32 + lrow*2] = {rf0, rf1} bf16 pair
    {
        int r = tid & 127, half = tid >> 7;
        int slot = (r >> 5) * 32 + (r & 15) * 2 + ((r >> 4) & 1);
        const float* xp = x + (size_t)(row0 + r) * NE + e0;
        #pragma unroll
        for (int c4 = 0; c4 < 4; ++c4) {
            int eb = half * 16 + c4 * 4;
            if (eb < ne) {
                float4 v = *(const float4*)(xp + eb);
                xts[(eb + 0) * 128 + slot] = f2bf(v.x);
                xts[(eb + 1) * 128 + slot] = f2bf(v.y);
                xts[(eb + 2) * 128 + slot] = f2bf(v.z);
                xts[(eb + 3) * 128 + slot] = f2bf(v.w);
            }
        }
    }
    // ---- stage W1/b1 f32 slices (coalesced) ----
    {
        int e = tid >> 3;
        int h = (tid & 7) * 8;
        if (e < ne) {
            const float* wsrc = W1 + (size_t)(e0 + e) * HID + h;
            const float* bsrc = b1 + (size_t)(e0 + e) * HID + h;
            *(float4*)&w1l[e * 64 + h]     = *(const float4*)(wsrc);
            *(float4*)&w1l[e * 64 + h + 4] = *(const float4*)(wsrc + 4);
            *(float4*)&b1l[e * 64 + h]     = *(const float4*)(bsrc);
            *(float4*)&b1l[e * 64 + h + 4] = *(const float4*)(bsrc + 4);
        }
    }

    // ---- stage: one 14336 B blob -> LDS (896 x 16B chunks, 256 threads) ----
    auto stage = [&](int buf, int e) {
        const unsigned* g = blob + (size_t)e * BLOBU;
        unsigned* lbase = (unsigned*)(smem + buf * EXPB);
        #pragma unroll
        for (int k = 0; k < 3; ++k) {
            int off = (k * 256 + tid) * 4;
            __builtin_amdgcn_global_load_lds(
                (const __attribute__((address_space(1))) unsigned*)(g + off),
                (__attribute__((address_space(3))) unsigned*)(lbase + off),
                16, 0, 0);
        }
        if (tid < 128) {
            int off = (768 + tid) * 4;
            __builtin_amdgcn_global_load_lds(
                (const __attribute__((address_space(1))) unsigned*)(g + off),
                (__attribute__((address_space(3))) unsigned*)(lbase + off),
                16, 0, 0);
        }
    };

    stage(0, e0);
    __syncthreads();   // buf0 + xts + w1/b1 ready

    f32x4 acc[2][7];   // 56 AGPR -> 3 waves/SIMD fits
    #pragma unroll
    for (int rf = 0; rf < 2; ++rf)
        #pragma unroll
        for (int t = 0; t < 7; ++t)
            acc[rf][t] = (f32x4){0.f, 0.f, 0.f, 0.f};

    unsigned zero = 0;
    int cur = 0;
    for (int ei = 0; ei < ne; ++ei) {
        if (ei + 1 < ne) stage(cur ^ 1, e0 + ei + 1);   // async prefetch next expert

        const unsigned char* bufc = smem + cur * EXPB;
        unsigned xw = *(const unsigned*)&xts[ei * 128 + wave * 32 + lrow * 2];
        f32x2 xx0 = {bf2f((unsigned short)(xw & 0xffffu)), bf2f((unsigned short)(xw & 0xffffu))};
        f32x2 xx1 = {bf2f((unsigned short)(xw >> 16)),     bf2f((unsigned short)(xw >> 16))};

        #pragma unroll
        for (int ksh = 0; ksh < 2; ++ksh) {
            const int hb = ksh * 32 + kg * 8;
            // broadcast b128 reads (16-lane-uniform -> ~free LDS BW)
            const f32x2* wp = (const f32x2*)&w1l[ei * 64 + hb];   // 4 pairs w
            const f32x2* bp = (const f32x2*)&b1l[ei * 64 + hb];   // 4 pairs b

            short8 a0, a1;
            unsigned* a0u = (unsigned*)&a0;
            unsigned* a1u = (unsigned*)&a1;
            #pragma unroll
            for (int q = 0; q < 4; ++q) {
                a0u[q] = pk_h(xx0, wp[q], bp[q], zero);
                a1u[q] = pk_h(xx1, wp[q], bp[q], zero);
            }

            __builtin_amdgcn_s_setprio(1);
            #pragma unroll
            for (int t = 0; t < 7; ++t) {
                short8 bf = *(const short8*)(bufc + ((ksh * 7 + t) << 10) + lane * 16);
                acc[0][t] = __builtin_amdgcn_mfma_f32_16x16x32_bf16(a0, bf, acc[0][t], 0, 0, 0);
                acc[1][t] = __builtin_amdgcn_mfma_f32_16x16x32_bf16(a1, bf, acc[1][t], 0, 0, 0);
            }
            __builtin_amdgcn_s_setprio(0);
        }
        __syncthreads();   // next buffer landed during compute
        cur ^= 1;
    }

    // ---- epilogue: bf16 partials [ks][NB][NVP]; C/D col = lane&15, row = kg*4+reg ----
    unsigned short* dst = part + (size_t)ks * (NB * NVP);
    #pragma unroll
    for (int rf = 0; rf < 2; ++rf) {
        #pragma unroll
        for (int t = 0; t < 7; ++t) {
            int col = t * 16 + lrow;
            size_t base = (size_t)(row0 + wave * 32 + rf * 16 + kg * 4) * NVP + col;
            #pragma unroll
            for (int r = 0; r < 4; ++r)
                dst[base + (size_t)r * NVP] = (unsigned short)cvtbf(acc[rf][t][r]);
        }
    }
}

// ---------------- reduce: out = bias + sum_k bf16 part[k] ----------------
__global__ void reduce3(const unsigned short* __restrict__ part, float* __restrict__ out) {
    int idx = blockIdx.x * 256 + threadIdx.x;   // < NB*14 = 57344
    if (idx >= NB * (NVP / 8)) return;
    int b = idx / (NVP / 8);
    int g = idx - b * (NVP / 8);
    int c0 = g * 8;
    float s[8];
    #pragma unroll
    for (int j = 0; j < 8; ++j)
        s[j] = (c0 + j < NV) ? g_bsum[c0 + j] : 0.f;
    size_t off = (size_t)b * NVP + c0;
    #pragma unroll 4
    for (int k = 0; k < ESPLIT; ++k) {
        ushort8 v = *(const ushort8*)&part[(size_t)k * (NB * NVP) + off];
        #pragma unroll
        for (int j = 0; j < 8; ++j)
            s[j] += bf2f(v[j]);
    }
    #pragma unroll
    for (int j = 0; j < 8; ++j)
        if (c0 + j < NV) out[(size_t)b * NV + c0 + j] = s[j];
}

// ---------------- fallback (tiny ws): in-kernel convert + atomics ----------------
#define LDW 72
__global__ __launch_bounds__(256, 3) void moe_fallback(
    const float* __restrict__ x, const float* __restrict__ W1,
    const float* __restrict__ b1, const float* __restrict__ W2,
    float* __restrict__ dst)
{
    __shared__ unsigned short w2t[8192];
    const int tid  = threadIdx.x;
    const int lane = tid & 63;
    const int lrow = lane & 15;
    const int kg   = lane >> 4;
    const int wave = tid >> 6;
    const int row0 = blockIdx.x * 128 + wave * 32;
    const int e0 = blockIdx.y * 32;
    const int e1 = min(NE, e0 + 32);

    f32x4 acc[2][7];
    #pragma unroll
    for (int rf = 0; rf < 2; ++rf)
        #pragma unroll
        for (int t = 0; t < 7; ++t)
            acc[rf][t] = (f32x4){0.f, 0.f, 0.f, 0.f};

    const float* xr0 = x + (size_t)(row0 + lrow) * NE;
    const float* xr1 = x + (size_t)(row0 + 16 + lrow) * NE;

    for (int e = e0; e < e1; ++e) {
        __syncthreads();
        const float* src = W2 + (size_t)e * (HID * NV);
        unsigned* w2t32 = (unsigned*)w2t;
        #pragma unroll
        for (int k = 0; k < 13; ++k) {
            int i = tid + k * 256;
            if (i < (HID / 2) * NV) {
                int a3  = i / 400;
                int rem = i - a3 * 400;
                int bv  = rem >> 2;
                int c   = rem & 3;
                int hh2 = a3 * 4 + c;
                float f0 = src[(2 * hh2) * NV + bv];
                float f1 = src[(2 * hh2 + 1) * NV + bv];
                w2t32[bv * (LDW / 2) + hh2] = pkbf(f0, f1);
            }
        }
        __syncthreads();

        float xv0 = xr0[e];
        float xv1 = xr1[e];
        const float* w1p = W1 + e * HID;
        const float* b1p = b1 + e * HID;
        #pragma unroll
        for (int ksh = 0; ksh < 2; ++ksh) {
            const int hb = ksh * 32 + kg * 8;
            f32x4 w1lo = *(const f32x4*)(w1p + hb);
            f32x4 w1hi = *(const f32x4*)(w1p + hb + 4);
            f32x4 blo  = *(const f32x4*)(b1p + hb);
            f32x4 bhi  = *(const f32x4*)(b1p + hb + 4);
            short8 a0, a1;
            #pragma unroll
            for (int j = 0; j < 4; ++j) {
                a0[j]     = cvtbf(fmaxf(fmaf(xv0, w1lo[j], blo[j]), 0.f));
                a0[j + 4] = cvtbf(fmaxf(fmaf(xv0, w1hi[j], bhi[j]), 0.f));
                a1[j]     = cvtbf(fmaxf(fmaf(xv1, w1lo[j], blo[j]), 0.f));
                a1[j + 4] = cvtbf(fmaxf(fmaf(xv1, w1hi[j], bhi[j]), 0.f));
            }
            #pragma unroll
            for (int t = 0; t < 7; ++t) {
                short8 bf = *(const short8*)&w2t[(t * 16 + lrow) * LDW + hb];
                acc[0][t] = __builtin_amdgcn_mfma_f32_16x16x32_bf16(a0, bf, acc[0][t], 0, 0, 0);
                acc[1][t] = __builtin_amdgcn_mfma_f32_16x16x32_bf16(a1, bf, acc[1][t], 0, 0, 0);
            }
        }
    }

    #pragma unroll
    for (int rf = 0; rf < 2; ++rf) {
        #pragma unroll
        for (int t = 0; t < 7; ++t) {
            int col = t * 16 + lrow;
            if (col < NV) {
                size_t base = (size_t)(row0 + rf * 16 + kg * 4) * NV + col;
                #pragma unroll
                for (int r = 0; r < 4; ++r)
                    atomicAdd(&dst[base + (size_t)r * NV], acc[rf][t][r]);
            }
        }
    }
}

extern "C" void kernel_launch(void* const* d_in, const int* in_sizes, int n_in,
                              void* d_out, int out_size, void* d_ws, size_t ws_size,
                              hipStream_t stream) {
    const float* x  = (const float*)d_in[0];
    const float* W1 = (const float*)d_in[1];
    const float* b1 = (const float*)d_in[2];
    const float* W2 = (const float*)d_in[3];
    const float* b2 = (const float*)d_in[4];
    float* out = (float*)d_out;

    const size_t BLOB_BYTES = (size_t)NE * BLOBU * 4;          // 14,336,000
    const size_t PART_BYTES = (size_t)ESPLIT * NB * NVP * 2;   // 29,360,128

    bias_kernel<<<NV, 256, 0, stream>>>(b2);

    if (ws_size >= BLOB_BYTES + PART_BYTES) {
        unsigned* blob = (unsigned*)d_ws;
        unsigned short* part = (unsigned short*)((char*)d_ws + BLOB_BYTES);
        prepass7<<<NE, 256, 0, stream>>>(W2, blob);
        moe17<<<1024, 256, 0, stream>>>(x, W1, b1, blob, part);
        reduce3<<<(NB * (NVP / 8) + 255) / 256, 256, 0, stream>>>(part, out);
    } else {
        init_kernel<<<(NB * NV + 255) / 256, 256, 0, stream>>>(out);
        moe_fallback<<<dim3(NB / 128, ESPLIT), 256, 0, stream>>>(x, W1, b1, W2, out);
    }
}

// Round 19
// 77.083 us; speedup vs baseline: 1.2093x; 1.2093x over previous
//
#include <hip/hip_runtime.h>
#include <hip/hip_bf16.h>

#define NV 100        // n_vars
#define HID 64        // hidden
#define NE 1000       // experts
#define NB 4096       // batch
#define ESPLIT 32     // K-split count
#define BLOBU 3584    // u32/expert: W2 frags only (14336 B)
#define NVP 112       // padded cols in bf16 partials

typedef __attribute__((ext_vector_type(8))) short short8;   // MFMA A/B frag
typedef __attribute__((ext_vector_type(8))) unsigned short ushort8;
typedef __attribute__((ext_vector_type(4))) float f32x4;    // MFMA C/D frag
typedef __attribute__((ext_vector_type(2))) float f32x2;    // packed-math pair
typedef __attribute__((ext_vector_type(4))) unsigned u32x4;
typedef __attribute__((ext_vector_type(4))) unsigned short u16x4;

__device__ __align__(16) float g_bsum[NV];

__device__ __forceinline__ unsigned short f2bf(float f) {
    return (unsigned short)__builtin_bit_cast(short, (__bf16)f);
}
__device__ __forceinline__ short cvtbf(float f) {
    return __builtin_bit_cast(short, (__bf16)f);
}
__device__ __forceinline__ float bf2f(unsigned short s) {
    union { unsigned u; float f; } v; v.u = ((unsigned)s) << 16;
    return v.f;
}
__device__ __forceinline__ unsigned pkbf(float a, float b) {
    return (unsigned)f2bf(a) | ((unsigned)f2bf(b) << 16);
}

// packed h-pair: {h0,h1} = relu_bf16(cvt_pk(pk_fma(x·w + b)))  [r14-proven]
__device__ __forceinline__ unsigned pk_h(f32x2 xx, f32x2 w, f32x2 b, unsigned zero) {
    f32x2 d;
    asm("v_pk_fma_f32 %0, %1, %2, %3" : "=v"(d) : "v"(xx), "v"(w), "v"(b));
    unsigned u;
    asm("v_cvt_pk_bf16_f32 %0, %1, %2" : "=v"(u) : "v"(d.x), "v"(d.y));
    asm("v_pk_max_i16 %0, %1, %2" : "=v"(u) : "v"(u), "v"(zero));
    return u;
}

// balanced expert split: 26 splits of 32, 6 splits of 28
__device__ __host__ __forceinline__ void esplit_range(int ks, int* pe0, int* pne) {
    int e0 = (ks < 26) ? 32 * ks : 832 + 28 * (ks - 26);
    int ne = (ks < 26) ? 32 : 28;
    *pe0 = e0; *pne = ne;
}

// ---------------- bias: g_bsum[v] = sum_e b2[e*NV + v] ----------------
__global__ void bias_kernel(const float* __restrict__ b2) {
    int v = blockIdx.x;
    float s = 0.f;
    for (int e = threadIdx.x; e < NE; e += 256)
        s += b2[e * NV + v];
    __shared__ float red[4];
    for (int off = 32; off; off >>= 1) s += __shfl_down(s, off, 64);
    if ((threadIdx.x & 63) == 0) red[threadIdx.x >> 6] = s;
    __syncthreads();
    if (threadIdx.x == 0) g_bsum[v] = red[0] + red[1] + red[2] + red[3];
}

// ---------------- init (fallback path only) ----------------
__global__ void init_kernel(float* __restrict__ out) {
    int idx = blockIdx.x * 256 + threadIdx.x;
    if (idx < NB * NV) out[idx] = g_bsum[idx % NV];
}

// ---------------- prepass: W2 -> frag-contiguous bf16, 14336 B/expert ----------------
__global__ void prepass7(const float* __restrict__ W2, unsigned* __restrict__ blob) {
    __shared__ float t[HID][NV + 1];
    int e = blockIdx.x;
    const float* src = W2 + (size_t)e * (HID * NV);
    for (int i = threadIdx.x; i < HID * NV; i += 256) {
        int hh = i / NV;
        int v = i - hh * NV;
        t[hh][v] = src[i];
    }
    __syncthreads();
    unsigned* dst = blob + (size_t)e * BLOBU;
    for (int o = threadIdx.x; o < BLOBU; o += 256) {
        int f = o >> 8;
        int r = o & 255;
        int l = r >> 2;
        int q = r & 3;
        int ksh = f / 7, tt = f - 7 * ksh;
        int kg = l >> 4, lrow = l & 15;
        int h0 = ksh * 32 + kg * 8 + 2 * q;
        int v = tt * 16 + lrow;
        unsigned val = 0;
        if (v < NV) val = pkbf(t[h0][v], t[h0 + 1][v]);
        dst[o] = val;
    }
}

// ---------------- main: barrier-free, B in regs, SGB-interleaved MFMA/VALU ----------------
__global__ __launch_bounds__(256, 2) void moe16(
    const float* __restrict__ x, const float* __restrict__ W1,
    const float* __restrict__ b1, const unsigned* __restrict__ blob,
    unsigned short* __restrict__ part)
{
    __shared__ __align__(16) unsigned short xts[32 * 256];   // 16 KiB permuted x^T
    __shared__ __align__(16) float w1l[32 * 64];             // 8 KiB f32 W1 slice
    __shared__ __align__(16) float b1l[32 * 64];             // 8 KiB f32 b1 slice

    const int bid = blockIdx.x;
    const int xcd = bid & 7;
    const int jj  = bid >> 3;              // 0..63
    const int ks  = xcd * 4 + (jj & 3);    // 4 consecutive ksplits per XCD
    const int mb  = jj >> 2;               // 0..15

    const int tid  = threadIdx.x;
    const int lane = tid & 63;
    const int wave = tid >> 6;             // 0..3, rows wave*64 .. +63
    const int lrow = lane & 15;
    const int kg   = lane >> 4;

    const int row0 = mb * 256;
    int e0, ne; esplit_range(ks, &e0, &ne);

    // ---- stage x permuted: row r -> slot (r>>6)*64 + (r&15)*4 + ((r>>4)&3) ----
    {
        int r = tid;
        int slot = (r >> 6) * 64 + (r & 15) * 4 + ((r >> 4) & 3);
        const float* xp = x + (size_t)(row0 + r) * NE + e0;
        #pragma unroll
        for (int c4 = 0; c4 < 8; ++c4) {
            int eb = c4 * 4;
            if (eb < ne) {
                float4 v = *(const float4*)(xp + eb);
                xts[(eb + 0) * 256 + slot] = f2bf(v.x);
                xts[(eb + 1) * 256 + slot] = f2bf(v.y);
                xts[(eb + 2) * 256 + slot] = f2bf(v.z);
                xts[(eb + 3) * 256 + slot] = f2bf(v.w);
            }
        }
    }
    // ---- stage W1/b1 f32 slices (coalesced) ----
    {
        int e = tid >> 3;
        int h = (tid & 7) * 8;
        if (e < ne) {
            const float* wsrc = W1 + (size_t)(e0 + e) * HID + h;
            const float* bsrc = b1 + (size_t)(e0 + e) * HID + h;
            *(float4*)&w1l[e * 64 + h]     = *(const float4*)(wsrc);
            *(float4*)&w1l[e * 64 + h + 4] = *(const float4*)(wsrc + 4);
            *(float4*)&b1l[e * 64 + h]     = *(const float4*)(bsrc);
            *(float4*)&b1l[e * 64 + h + 4] = *(const float4*)(bsrc + 4);
        }
    }
    __syncthreads();   // the ONLY barrier

    f32x4 acc[4][7];
    #pragma unroll
    for (int rf = 0; rf < 4; ++rf)
        #pragma unroll
        for (int t = 0; t < 7; ++t)
            acc[rf][t] = (f32x4){0.f, 0.f, 0.f, 0.f};

    // register B double-buffer (per-ksh), loaded straight from L2
    u32x4 B0[7], B1[7];
    const int boff = lane * 4;

    auto LOADS0 = [&](const unsigned* g) {
        #pragma unroll
        for (int t = 0; t < 7; ++t)
            B0[t] = *(const u32x4*)(g + t * 256 + boff);
    };
    auto LOADS1 = [&](const unsigned* g) {
        #pragma unroll
        for (int t = 0; t < 7; ++t)
            B1[t] = *(const u32x4*)(g + (7 + t) * 256 + boff);
    };

    unsigned zero = 0;

    // DOUBLE-buffered W slice sets: WcA=(e,ksh0), WcB=(e,ksh1) — no WAR between
    // BUILD reads and next WLOAD writes, so ds_reads can float early.
    float4 WcA[4], WcB[4];
    auto WLOADA = [&](int e) {
        const int hb = kg * 8;
        WcA[0] = *(const float4*)&w1l[e * 64 + hb];
        WcA[1] = *(const float4*)&w1l[e * 64 + hb + 4];
        WcA[2] = *(const float4*)&b1l[e * 64 + hb];
        WcA[3] = *(const float4*)&b1l[e * 64 + hb + 4];
    };
    auto WLOADB = [&](int e) {
        const int hb = 32 + kg * 8;
        WcB[0] = *(const float4*)&w1l[e * 64 + hb];
        WcB[1] = *(const float4*)&w1l[e * 64 + hb + 4];
        WcB[2] = *(const float4*)&b1l[e * 64 + hb];
        WcB[3] = *(const float4*)&b1l[e * 64 + hb + 4];
    };

    // packed-math A-build: 12 VALU per rf (48 per call)
    auto BUILD = [&](short8* afr, const float* xv, const float4* Wc) {
        const f32x2* wp = (const f32x2*)&Wc[0];
        #pragma unroll
        for (int rf = 0; rf < 4; ++rf) {
            f32x2 xx = {xv[rf], xv[rf]};
            unsigned* au = (unsigned*)&afr[rf];
            au[0] = pk_h(xx, wp[0], wp[4], zero);
            au[1] = pk_h(xx, wp[1], wp[5], zero);
            au[2] = pk_h(xx, wp[2], wp[6], zero);
            au[3] = pk_h(xx, wp[3], wp[7], zero);
        }
    };

    // SGB script: interleave 1 MFMA : 2 VALU so the wave feeds both pipes itself
    auto SGB_INTERLEAVE = [&]() {
        #pragma unroll
        for (int i = 0; i < 28; ++i) {
            __builtin_amdgcn_sched_group_barrier(0x008, 1, 0);  // 1 MFMA
            __builtin_amdgcn_sched_group_barrier(0x002, 2, 0);  // 2 VALU
        }
    };

    const unsigned* gcur = blob + (size_t)e0 * BLOBU;
    LOADS0(gcur);
    LOADS1(gcur);

    const unsigned short* xrow = &xts[wave * 64 + lrow * 4];

    short8 afrA[4], afrB[4];
    float xvC[4], xvN[4];
    {
        u16x4 xq = *(const u16x4*)xrow;
        #pragma unroll
        for (int rf = 0; rf < 4; ++rf) xvC[rf] = bf2f(xq[rf]);
    }
    WLOADA(0);
    WLOADB(0);
    BUILD(afrA, xvC, WcA);   // (e0, ksh0)

    for (int ei = 0; ei < ne; ++ei) {
        const int en = (ei + 1 < ne) ? ei + 1 : ei;
        const unsigned* gnext = blob + (size_t)(e0 + en) * BLOBU;

        // ---- phase A: cluster(afrA×B0) ∥ BUILD(afrB, ksh1) — SGB-interleaved ----
        BUILD(afrB, xvC, WcB);     // VALU to interleave into cluster A
        WLOADA(en);                // ds_reads float early (no WAR: separate set)
        {
            u16x4 xq = *(const u16x4*)(xrow + en * 256);
            #pragma unroll
            for (int rf = 0; rf < 4; ++rf) xvN[rf] = bf2f(xq[rf]);
        }
        #pragma unroll
        for (int t = 0; t < 7; ++t) {
            short8 bf = __builtin_bit_cast(short8, B0[t]);
            #pragma unroll
            for (int rf = 0; rf < 4; ++rf)
                acc[rf][t] = __builtin_amdgcn_mfma_f32_16x16x32_bf16(afrA[rf], bf, acc[rf][t], 0, 0, 0);
        }
        SGB_INTERLEAVE();
        LOADS0(gnext);             // WAR on B0: lands after cluster A issues

        // ---- phase B: cluster(afrB×B1) ∥ BUILD(afrA, next ksh0) — SGB-interleaved ----
        BUILD(afrA, xvN, WcA);     // VALU to interleave into cluster B
        WLOADB(en);
        #pragma unroll
        for (int t = 0; t < 7; ++t) {
            short8 bf = __builtin_bit_cast(short8, B1[t]);
            #pragma unroll
            for (int rf = 0; rf < 4; ++rf)
                acc[rf][t] = __builtin_amdgcn_mfma_f32_16x16x32_bf16(afrB[rf], bf, acc[rf][t], 0, 0, 0);
        }
        SGB_INTERLEAVE();
        LOADS1(gnext);

        #pragma unroll
        for (int rf = 0; rf < 4; ++rf) xvC[rf] = xvN[rf];
    }

    // ---- epilogue: bf16 partials [ks][NB][112]; C/D col = lane&15, row = kg*4+reg ----
    unsigned short* dst = part + (size_t)ks * (NB * NVP);
    #pragma unroll
    for (int rf = 0; rf < 4; ++rf) {
        #pragma unroll
        for (int t = 0; t < 7; ++t) {
            int col = t * 16 + lrow;
            size_t base = (size_t)(row0 + wave * 64 + rf * 16 + kg * 4) * NVP + col;
            #pragma unroll
            for (int r = 0; r < 4; ++r)
                dst[base + (size_t)r * NVP] = (unsigned short)cvtbf(acc[rf][t][r]);
        }
    }
}

// ---------------- reduce: out = bias + sum_k bf16 part[k] ----------------
__global__ void reduce3(const unsigned short* __restrict__ part, float* __restrict__ out) {
    int idx = blockIdx.x * 256 + threadIdx.x;   // < NB*14 = 57344
    if (idx >= NB * (NVP / 8)) return;
    int b = idx / (NVP / 8);
    int g = idx - b * (NVP / 8);
    int c0 = g * 8;
    float s[8];
    #pragma unroll
    for (int j = 0; j < 8; ++j)
        s[j] = (c0 + j < NV) ? g_bsum[c0 + j] : 0.f;
    size_t off = (size_t)b * NVP + c0;
    #pragma unroll 4
    for (int k = 0; k < ESPLIT; ++k) {
        ushort8 v = *(const ushort8*)&part[(size_t)k * (NB * NVP) + off];
        #pragma unroll
        for (int j = 0; j < 8; ++j)
            s[j] += bf2f(v[j]);
    }
    #pragma unroll
    for (int j = 0; j < 8; ++j)
        if (c0 + j < NV) out[(size_t)b * NV + c0 + j] = s[j];
}

// ---------------- fallback (tiny ws): in-kernel convert + atomics ----------------
#define LDW 72
__global__ __launch_bounds__(256, 3) void moe_fallback(
    const float* __restrict__ x, const float* __restrict__ W1,
    const float* __restrict__ b1, const float* __restrict__ W2,
    float* __restrict__ dst)
{
    __shared__ unsigned short w2t[8192];
    const int tid  = threadIdx.x;
    const int lane = tid & 63;
    const int lrow = lane & 15;
    const int kg   = lane >> 4;
    const int wave = tid >> 6;
    const int row0 = blockIdx.x * 128 + wave * 32;
    const int e0 = blockIdx.y * 32;
    const int e1 = min(NE, e0 + 32);

    f32x4 acc[2][7];
    #pragma unroll
    for (int rf = 0; rf < 2; ++rf)
        #pragma unroll
        for (int t = 0; t < 7; ++t)
            acc[rf][t] = (f32x4){0.f, 0.f, 0.f, 0.f};

    const float* xr0 = x + (size_t)(row0 + lrow) * NE;
    const float* xr1 = x + (size_t)(row0 + 16 + lrow) * NE;

    for (int e = e0; e < e1; ++e) {
        __syncthreads();
        const float* src = W2 + (size_t)e * (HID * NV);
        unsigned* w2t32 = (unsigned*)w2t;
        #pragma unroll
        for (int k = 0; k < 13; ++k) {
            int i = tid + k * 256;
            if (i < (HID / 2) * NV) {
                int a3  = i / 400;
                int rem = i - a3 * 400;
                int bv  = rem >> 2;
                int c   = rem & 3;
                int hh2 = a3 * 4 + c;
                float f0 = src[(2 * hh2) * NV + bv];
                float f1 = src[(2 * hh2 + 1) * NV + bv];
                w2t32[bv * (LDW / 2) + hh2] = pkbf(f0, f1);
            }
        }
        __syncthreads();

        float xv0 = xr0[e];
        float xv1 = xr1[e];
        const float* w1p = W1 + e * HID;
        const float* b1p = b1 + e * HID;
        #pragma unroll
        for (int ksh = 0; ksh < 2; ++ksh) {
            const int hb = ksh * 32 + kg * 8;
            f32x4 w1lo = *(const f32x4*)(w1p + hb);
            f32x4 w1hi = *(const f32x4*)(w1p + hb + 4);
            f32x4 blo  = *(const f32x4*)(b1p + hb);
            f32x4 bhi  = *(const f32x4*)(b1p + hb + 4);
            short8 a0, a1;
            #pragma unroll
            for (int j = 0; j < 4; ++j) {
                a0[j]     = cvtbf(fmaxf(fmaf(xv0, w1lo[j], blo[j]), 0.f));
                a0[j + 4] = cvtbf(fmaxf(fmaf(xv0, w1hi[j], bhi[j]), 0.f));
                a1[j]     = cvtbf(fmaxf(fmaf(xv1, w1lo[j], blo[j]), 0.f));
                a1[j + 4] = cvtbf(fmaxf(fmaf(xv1, w1hi[j], bhi[j]), 0.f));
            }
            #pragma unroll
            for (int t = 0; t < 7; ++t) {
                short8 bf = *(const short8*)&w2t[(t * 16 + lrow) * LDW + hb];
                acc[0][t] = __builtin_amdgcn_mfma_f32_16x16x32_bf16(a0, bf, acc[0][t], 0, 0, 0);
                acc[1][t] = __builtin_amdgcn_mfma_f32_16x16x32_bf16(a1, bf, acc[1][t], 0, 0, 0);
            }
        }
    }

    #pragma unroll
    for (int rf = 0; rf < 2; ++rf) {
        #pragma unroll
        for (int t = 0; t < 7; ++t) {
            int col = t * 16 + lrow;
            if (col < NV) {
                size_t base = (size_t)(row0 + rf * 16 + kg * 4) * NV + col;
                #pragma unroll
                for (int r = 0; r < 4; ++r)
                    atomicAdd(&dst[base + (size_t)r * NV], acc[rf][t][r]);
            }
        }
    }
}

extern "C" void kernel_launch(void* const* d_in, const int* in_sizes, int n_in,
                              void* d_out, int out_size, void* d_ws, size_t ws_size,
                              hipStream_t stream) {
    const float* x  = (const float*)d_in[0];
    const float* W1 = (const float*)d_in[1];
    const float* b1 = (const float*)d_in[2];
    const float* W2 = (const float*)d_in[3];
    const float* b2 = (const float*)d_in[4];
    float* out = (float*)d_out;

    const size_t BLOB_BYTES = (size_t)NE * BLOBU * 4;          // 14,336,000
    const size_t PART_BYTES = (size_t)ESPLIT * NB * NVP * 2;   // 29,360,128

    bias_kernel<<<NV, 256, 0, stream>>>(b2);

    if (ws_size >= BLOB_BYTES + PART_BYTES) {
        unsigned* blob = (unsigned*)d_ws;
        unsigned short* part = (unsigned short*)((char*)d_ws + BLOB_BYTES);
        prepass7<<<NE, 256, 0, stream>>>(W2, blob);
        moe16<<<512, 256, 0, stream>>>(x, W1, b1, blob, part);
        reduce3<<<(NB * (NVP / 8) + 255) / 256, 256, 0, stream>>>(part, out);
    } else {
        init_kernel<<<(NB * NV + 255) / 256, 256, 0, stream>>>(out);
        moe_fallback<<<dim3(NB / 128, ESPLIT), 256, 0, stream>>>(x, W1, b1, W2, out);
    }
}